// Round 11
// baseline (417.431 us; speedup 1.0000x reference)
//
#include <hip/hip_runtime.h>
#include <cstdint>
#include <cstddef>

// ---------------------------------------------------------------------------
// GAT 3-layer forward, MI355X.
// Round 22: bin branch of the fused kernel was the critical path (~45us: 196
// blocks, 2x edge reads, 3.2M LDS atomics, 196-RMW/word reservation burst).
// R20 taught that atomic cost scales with RMWs-per-word (4096/word = 573us).
// Per-NODE counters have only ~32 RMWs/word -> classic 3-step CSR build:
//  (1) per-node histogram fused into the gemm1 dispatch (grid-stride, no LDS,
//      no barriers, ONE edge read),
//  (2) 1-block 1024-thread shfl prefix scan over 50K counts (~3us),
//  (3) scatter: p=atomicAdd(&ccur[d],1); csr[rowptr[d]+p]=s (2048 blocks).
// fine_sort deleted. Within-node order stays atomic-timing-dependent exactly
// as before (fp reorder noise << threshold). csr format unchanged.
// ---------------------------------------------------------------------------

__device__ __forceinline__ float leaky(float v) { return v > 0.f ? v : 0.2f * v; }

__device__ __forceinline__ unsigned short f2bf(float x) {
    unsigned int u = __float_as_uint(x);
    u = (u + 0x7FFFu + ((u >> 16) & 1u)) >> 16;   // RNE
    return (unsigned short)u;
}
__device__ __forceinline__ float bf2f(unsigned short b) {
    return __uint_as_float(((unsigned int)b) << 16);
}
__device__ __forceinline__ float bfhi(unsigned int d) {
    return __uint_as_float(d & 0xFFFF0000u);
}
__device__ __forceinline__ float bflo(unsigned int d) {
    return __uint_as_float(d << 16);
}

typedef _Float16 half8 __attribute__((ext_vector_type(8)));
typedef float f32x4 __attribute__((ext_vector_type(4)));

#define CTILE  8192              // edges per hist block
#define NPAD   53248             // ncnt padding: 13 * 4096 (scan chunk size)

// -------------------- fused: per-node histogram + gemm1 MFMA --------------------

template <int FIN>
__global__ __launch_bounds__(256) void coarse_gemm1_kernel(
    const int* __restrict__ ei, int* __restrict__ ncnt, int E, int cblocks,
    const float* __restrict__ X, const float* __restrict__ W,
    const float* __restrict__ avs, const float* __restrict__ avd,
    unsigned short* __restrict__ hb, float* __restrict__ asrc,
    float* __restrict__ adst, int N) {

    if ((int)blockIdx.x < cblocks) {
        // -------- per-node histogram: ~32 RMWs/word, no LDS, no barriers ----
        int e0 = blockIdx.x * CTILE;
        int e1 = min(E, e0 + CTILE);
        for (int e = e0 + threadIdx.x; e < e1; e += 256)
            atomicAdd(&ncnt[ei[E + e]], 1);
        return;
    }

    // ---------------- gemm1: MFMA, W-in-VGPR fp16 (R15, verbatim) ----------
    constexpr int FOUT = 48;
    constexpr int KK = FIN / 32;
    static_assert(FIN % 32 == 0, "FIN multiple of 32");

    const int bid  = (int)blockIdx.x - cblocks;
    const int wid  = __builtin_amdgcn_readfirstlane(threadIdx.x >> 6);
    const int lane = threadIdx.x & 63;
    const int col  = lane & 15;
    const int grp  = lane >> 4;
    const int wbase = bid * 64 + wid * 16;

    int arow = wbase + col;
    if (arow >= N) arow = N - 1;
    const float* xrow = X + (size_t)arow * FIN + grp * 8;

    half8 Bf[3][KK];
#pragma unroll
    for (int t = 0; t < 3; t++) {
#pragma unroll
        for (int kk = 0; kk < KK; kk++) {
            const float* wp = W + (size_t)(kk * 32 + grp * 8) * FOUT + t * 16 + col;
#pragma unroll
            for (int j = 0; j < 8; j++)
                Bf[t][kk][j] = (_Float16)wp[(size_t)j * FOUT];
        }
    }

    f32x4 acc0 = {0.f, 0.f, 0.f, 0.f};
    f32x4 acc1 = {0.f, 0.f, 0.f, 0.f};
    f32x4 acc2 = {0.f, 0.f, 0.f, 0.f};

#pragma unroll
    for (int kk = 0; kk < KK; kk++) {
        float4 xa = *(const float4*)(xrow + kk * 32);
        float4 xb = *(const float4*)(xrow + kk * 32 + 4);
        float xs[8] = {xa.x, xa.y, xa.z, xa.w, xb.x, xb.y, xb.z, xb.w};
        half8 ah, al;
#pragma unroll
        for (int j = 0; j < 8; j++) {
            _Float16 h = (_Float16)xs[j];
            ah[j] = h;
            al[j] = (_Float16)(xs[j] - (float)h);
        }
        acc0 = __builtin_amdgcn_mfma_f32_16x16x32_f16(ah, Bf[0][kk], acc0, 0, 0, 0);
        acc1 = __builtin_amdgcn_mfma_f32_16x16x32_f16(ah, Bf[1][kk], acc1, 0, 0, 0);
        acc2 = __builtin_amdgcn_mfma_f32_16x16x32_f16(ah, Bf[2][kk], acc2, 0, 0, 0);
        acc0 = __builtin_amdgcn_mfma_f32_16x16x32_f16(al, Bf[0][kk], acc0, 0, 0, 0);
        acc1 = __builtin_amdgcn_mfma_f32_16x16x32_f16(al, Bf[1][kk], acc1, 0, 0, 0);
        acc2 = __builtin_amdgcn_mfma_f32_16x16x32_f16(al, Bf[2][kk], acc2, 0, 0, 0);
    }

    float avs0 = avs[col], avs1 = avs[16 + col], avs2 = avs[32 + col];
    float avd0 = avd[col], avd1 = avd[16 + col], avd2 = avd[32 + col];

#pragma unroll
    for (int r = 0; r < 4; r++) {
        float ps = acc0[r] * avs0 + acc1[r] * avs1 + acc2[r] * avs2;
        float pd = acc0[r] * avd0 + acc1[r] * avd1 + acc2[r] * avd2;
#pragma unroll
        for (int off = 8; off; off >>= 1) {
            ps += __shfl_xor(ps, off, 64);
            pd += __shfl_xor(pd, off, 64);
        }
        int nd = wbase + grp * 4 + r;
        if (col == r && nd < N) { asrc[nd] = ps; adst[nd] = pd; }
    }

#pragma unroll
    for (int r = 0; r < 4; r++) {
        int nd = wbase + grp * 4 + r;
        if (nd < N) {
            unsigned short* hp = hb + (size_t)nd * 64 + col;
            hp[0]  = f2bf(acc0[r]);
            hp[16] = f2bf(acc1[r]);
            hp[32] = f2bf(acc2[r]);
        }
    }
}

// -------------------- rowptr prefix scan (1 block, 1024 threads) ------------
// 13 chunks x 4096 counts: per-thread 4, wave shfl-scan, 16-wave LDS combine,
// 2 barriers/chunk. ncnt is zero-padded to NPAD so int4 loads are unguarded.

__global__ __launch_bounds__(1024) void scan_kernel(
    const int* __restrict__ ncnt, int* __restrict__ rowptr, int N) {
    __shared__ int sh[16];
    const int t = threadIdx.x;
    const int lane = t & 63;
    const int wv = t >> 6;
    int carry = 0;
    for (int base = 0; base < N; base += 4096) {
        int idx = base + t * 4;
        int4 c = *(const int4*)(ncnt + idx);       // padded region is zero
        int ts = c.x + c.y + c.z + c.w;
        int incl = ts;
#pragma unroll
        for (int off = 1; off < 64; off <<= 1) {
            int v = __shfl_up(incl, off, 64);
            if (lane >= off) incl += v;
        }
        if (lane == 63) sh[wv] = incl;
        __syncthreads();
        int wbase = 0, total = 0;
#pragma unroll
        for (int j = 0; j < 16; j++) {
            int sj = sh[j];
            wbase += (j < wv) ? sj : 0;
            total += sj;
        }
        int o = carry + wbase + (incl - ts);
        if (idx < N)     rowptr[idx]     = o;
        if (idx + 1 < N) rowptr[idx + 1] = o + c.x;
        if (idx + 2 < N) rowptr[idx + 2] = o + c.x + c.y;
        if (idx + 3 < N) rowptr[idx + 3] = o + c.x + c.y + c.z;
        carry += total;
        __syncthreads();
    }
    if (t == 0) rowptr[N] = carry;   // == E
}

// -------------------- scatter: edges -> csr (per-node cursors) --------------

__global__ __launch_bounds__(256) void scatter_kernel(
    const int* __restrict__ ei, const int* __restrict__ rowptr,
    int* __restrict__ ccur, int* __restrict__ csr, int E) {
    const int stride = gridDim.x * 256;
    for (int e = blockIdx.x * 256 + threadIdx.x; e < E; e += stride) {
        int s = ei[e];
        int d = ei[E + e];
        int p = atomicAdd(&ccur[d], 1);
        csr[rowptr[d] + p] = s;
    }
}

// -------------------- layer-2 GEMM (R12 structure: fout split, s_load W) ----

template <int FIN, int FOUT, int FT>
__global__ __launch_bounds__(256) void gemm_sgpr_kernel(
    const float* __restrict__ X, const float* __restrict__ W,
    const float* __restrict__ avs, const float* __restrict__ avd,
    unsigned short* __restrict__ hb, float* __restrict__ asrc, float* __restrict__ adst,
    int N) {
    static_assert(4 * FT == FOUT, "FT must be FOUT/4");
    __shared__ float red[2][4][64];

    const int wid  = __builtin_amdgcn_readfirstlane(threadIdx.x >> 6); // wave id 0..3
    const int lane = threadIdx.x & 63;
    const int n    = blockIdx.x * 64 + lane;
    const int nc   = (n < N) ? n : N - 1;     // clamp loads; stores guarded
    const int fbase = wid * FT;               // uniform

    const float* xrow = X + (size_t)nc * FIN;

    float acc[FT];
#pragma unroll
    for (int c = 0; c < FT; c++) acc[c] = 0.f;

#pragma unroll
    for (int k = 0; k < FIN; k += 4) {
        float4 xv = *(const float4*)(xrow + k);
        const float* w0 = W + (size_t)k * FOUT + fbase;   // uniform base
#pragma unroll
        for (int c = 0; c < FT; c++) {
            acc[c] = fmaf(xv.x, w0[c],            acc[c]);
            acc[c] = fmaf(xv.y, w0[FOUT + c],     acc[c]);
            acc[c] = fmaf(xv.z, w0[2 * FOUT + c], acc[c]);
            acc[c] = fmaf(xv.w, w0[3 * FOUT + c], acc[c]);
        }
    }

    // alpha partials over this wave's fout subset (avs/avd loads are uniform)
    float ps = 0.f, pd = 0.f;
#pragma unroll
    for (int c = 0; c < FT; c++) {
        ps = fmaf(acc[c], avs[fbase + c], ps);
        pd = fmaf(acc[c], avd[fbase + c], pd);
    }
    red[0][wid][lane] = ps;
    red[1][wid][lane] = pd;

    // h store (bf16, padded 64-entry rows)
    if (n < N) {
        if constexpr ((FT & 1) == 0) {
            unsigned int* dst = (unsigned int*)(hb + (size_t)n * 64 + fbase);
#pragma unroll
            for (int c = 0; c < FT; c += 2) {
                unsigned int pk = (unsigned int)f2bf(acc[c]) |
                                  ((unsigned int)f2bf(acc[c + 1]) << 16);
                dst[c >> 1] = pk;
            }
        } else {
#pragma unroll
            for (int c = 0; c < FT; c++)
                hb[(size_t)n * 64 + fbase + c] = f2bf(acc[c]);
        }
    }

    __syncthreads();
    if (threadIdx.x < 64 && n < N) {
        float s = red[0][0][lane] + red[0][1][lane] + red[0][2][lane] + red[0][3][lane];
        float d = red[1][0][lane] + red[1][1][lane] + red[1][2][lane] + red[1][3][lane];
        asrc[n] = s;
        adst[n] = d;
    }
}

// -------------------- pipelined gather step (R17) --------------------

#define GATHER_STEP(NG)                                                        \
    {                                                                          \
        int   off_[NG];                                                        \
        uint2 hd_[NG];                                                         \
        float ww_[NG];                                                         \
        _Pragma("unroll")                                                      \
        for (int u = 0; u < NG; u++) off_[u] = offlds[wv][4 * u + q];          \
        _Pragma("unroll")                                                      \
        for (int u = 0; u < NG; u++)                                           \
            hd_[u] = *(const uint2*)(hbb + ((unsigned int)off_[u] + suboff));  \
        float we = (lane < cnt) ? __expf(leaky(as + ad_n)) : 0.f;              \
        wpart += we;                                                           \
        wlds[wv][lane] = we;                                                   \
        _Pragma("unroll")                                                      \
        for (int u = 0; u < NG; u++) ww_[u] = wlds[wv][4 * u + q];             \
        _Pragma("unroll")                                                      \
        for (int u = 0; u < NG; u++) {                                         \
            a0 = fmaf(ww_[u], bflo(hd_[u].x), a0);                             \
            a1 = fmaf(ww_[u], bfhi(hd_[u].x), a1);                             \
            a2 = fmaf(ww_[u], bflo(hd_[u].y), a2);                             \
            a3 = fmaf(ww_[u], bfhi(hd_[u].y), a3);                             \
        }                                                                      \
    }

// -------------------- pipelined quad-edge aggregation (R17) --------------------

template <int FOUT, bool RELU>
__global__ __launch_bounds__(256) void agg_pipe_kernel(
    const int* __restrict__ rowptr, const int* __restrict__ csr,
    const float* __restrict__ asrc, const float* __restrict__ adst,
    const unsigned short* __restrict__ hb, const float* __restrict__ bias,
    float* __restrict__ OUT, int N) {
    constexpr int NSUB = FOUT / 4;
    static_assert(FOUT % 4 == 0, "FOUT multiple of 4");
    __shared__ int   offlds[4][64];
    __shared__ float wlds[4][64];
    const int wv = threadIdx.x >> 6;
    int n = blockIdx.x * 4 + wv;
    if (n >= N) return;
    const int lane = threadIdx.x & 63;
    const int q    = lane >> 4;            // quarter 0..3 -> slot 4u+q
    const int sub  = lane & 15;
    const int subc = (sub < NSUB) ? sub : NSUB - 1;   // clamp: no padding fetch
    const unsigned int suboff = (unsigned int)subc * 8;
    const int rs = rowptr[n], re = rowptr[n + 1];
    const float ad_n = adst[n];
    const float wself = __expf(leaky(asrc[n] + ad_n));
    const char* hbb = (const char*)hb;

    float a0 = 0.f, a1 = 0.f, a2 = 0.f, a3 = 0.f;
    float wpart = 0.f;

    for (int base = rs; base < re; base += 64) {
        const int cnt = min(64, re - base);
        int ce = base + lane;
        if (ce >= re) ce = re - 1;                  // clamp load addr
        int sv = csr[ce];
        int sidx = (lane < cnt) ? sv : n;           // padded -> self row (w=0)
        offlds[wv][lane] = sidx << 7;
        float as = asrc[sidx];
        if (cnt <= 32) { GATHER_STEP(8) } else { GATHER_STEP(16) }
    }

    // softmax denominator
#pragma unroll
    for (int off = 32; off; off >>= 1) wpart += __shfl_xor(wpart, off, 64);
    const float ssum = wpart + wself;

    // combine quarters -> all lanes hold full sums for their sub
    a0 += __shfl_xor(a0, 16, 64); a0 += __shfl_xor(a0, 32, 64);
    a1 += __shfl_xor(a1, 16, 64); a1 += __shfl_xor(a1, 32, 64);
    a2 += __shfl_xor(a2, 16, 64); a2 += __shfl_xor(a2, 32, 64);
    a3 += __shfl_xor(a3, 16, 64); a3 += __shfl_xor(a3, 32, 64);

    // self term (post-combine: counted once)
    {
        uint2 sv = *(const uint2*)(hbb + (((unsigned int)n << 7) + suboff));
        a0 = fmaf(wself, bflo(sv.x), a0);
        a1 = fmaf(wself, bfhi(sv.x), a1);
        a2 = fmaf(wself, bflo(sv.y), a2);
        a3 = fmaf(wself, bfhi(sv.y), a3);
    }

    if (lane < NSUB) {                     // quarter 0, valid subs only
        const float inv = 1.f / (ssum + 1e-16f);
        float4 bv = *(const float4*)(bias + sub * 4);
        float4 o;
        o.x = a0 * inv + bv.x;
        o.y = a1 * inv + bv.y;
        o.z = a2 * inv + bv.z;
        o.w = a3 * inv + bv.w;
        if (RELU) {
            o.x = fmaxf(o.x, 0.f); o.y = fmaxf(o.y, 0.f);
            o.z = fmaxf(o.z, 0.f); o.w = fmaxf(o.w, 0.f);
        }
        *(float4*)(OUT + (size_t)n * FOUT + sub * 4) = o;
    }
}

// -------------------- pipelined agg layer 2, fused layer-3 GEMM (R17) -------

__global__ __launch_bounds__(256) void agg_pipe_h3_kernel(
    const int* __restrict__ rowptr, const int* __restrict__ csr,
    const float* __restrict__ asrc, const float* __restrict__ adst,
    const unsigned short* __restrict__ hb, const float* __restrict__ bias,
    const float* __restrict__ W3, float* __restrict__ h3, int N) {
    constexpr int FOUT = 60;
    constexpr int NSUB = FOUT / 4;         // 15
    __shared__ int   offlds[4][64];
    __shared__ float wlds[4][64];
    const int wv = threadIdx.x >> 6;
    int n = blockIdx.x * 4 + wv;
    if (n >= N) return;
    const int lane = threadIdx.x & 63;
    const int q    = lane >> 4;
    const int sub  = lane & 15;
    const int subc = (sub < NSUB) ? sub : NSUB - 1;
    const unsigned int suboff = (unsigned int)subc * 8;
    const int rs = rowptr[n], re = rowptr[n + 1];
    const float ad_n = adst[n];
    const float wself = __expf(leaky(asrc[n] + ad_n));
    const char* hbb = (const char*)hb;

    float a0 = 0.f, a1 = 0.f, a2 = 0.f, a3 = 0.f;
    float wpart = 0.f;

    for (int base = rs; base < re; base += 64) {
        const int cnt = min(64, re - base);
        int ce = base + lane;
        if (ce >= re) ce = re - 1;
        int sv = csr[ce];
        int sidx = (lane < cnt) ? sv : n;
        offlds[wv][lane] = sidx << 7;
        float as = asrc[sidx];
        if (cnt <= 32) { GATHER_STEP(8) } else { GATHER_STEP(16) }
    }

#pragma unroll
    for (int off = 32; off; off >>= 1) wpart += __shfl_xor(wpart, off, 64);
    const float ssum = wpart + wself;

    a0 += __shfl_xor(a0, 16, 64); a0 += __shfl_xor(a0, 32, 64);
    a1 += __shfl_xor(a1, 16, 64); a1 += __shfl_xor(a1, 32, 64);
    a2 += __shfl_xor(a2, 16, 64); a2 += __shfl_xor(a2, 32, 64);
    a3 += __shfl_xor(a3, 16, 64); a3 += __shfl_xor(a3, 32, 64);

    {
        uint2 sv = *(const uint2*)(hbb + (((unsigned int)n << 7) + suboff));
        a0 = fmaf(wself, bflo(sv.x), a0);
        a1 = fmaf(wself, bfhi(sv.x), a1);
        a2 = fmaf(wself, bflo(sv.y), a2);
        a3 = fmaf(wself, bfhi(sv.y), a3);
    }

    // act2 = relu(acc/ssum + bias); fold layer-3 GEMM: t = dot(act2, W3)
    float t = 0.f;
    {
        const float inv = 1.f / (ssum + 1e-16f);
        float4 bv = *(const float4*)(bias + subc * 4);
        float4 wv3 = *(const float4*)(W3 + subc * 4);
        float o0 = fmaxf(a0 * inv + bv.x, 0.f);
        float o1 = fmaxf(a1 * inv + bv.y, 0.f);
        float o2 = fmaxf(a2 * inv + bv.z, 0.f);
        float o3 = fmaxf(a3 * inv + bv.w, 0.f);
        if (sub < NSUB)
            t = o0 * wv3.x + o1 * wv3.y + o2 * wv3.z + o3 * wv3.w;
    }
#pragma unroll
    for (int off = 8; off; off >>= 1) t += __shfl_xor(t, off, 64);   // within quarter
    if (lane == 0) h3[n] = t;
}

// -------------------- layer-3 aggregation --------------------

__global__ __launch_bounds__(256) void agg1_kernel(
    const int* __restrict__ rowptr, const int* __restrict__ csr,
    const float* __restrict__ h3,
    const float* __restrict__ as3p, const float* __restrict__ ad3p,
    const float* __restrict__ bias, float* __restrict__ OUT, int N) {
    int n = blockIdx.x * 4 + (threadIdx.x >> 6);
    if (n >= N) return;
    int lane = threadIdx.x & 63;
    int rs = rowptr[n], re = rowptr[n + 1];
    const float a_s = as3p[0];
    float hn = h3[n];
    float adn = ad3p[0] * hn;
    float wself = __expf(leaky(a_s * hn + adn));

    float ssum = 0.f, accv = 0.f;
    for (int e = rs + lane; e < re; e += 64) {
        float hs = h3[csr[e]];
        float w = __expf(leaky(a_s * hs + adn));
        ssum += w;
        accv = fmaf(w, hs, accv);
    }
#pragma unroll
    for (int off = 32; off; off >>= 1) {
        ssum += __shfl_xor(ssum, off, 64);
        accv += __shfl_xor(accv, off, 64);
    }
    ssum += wself;
    accv = fmaf(wself, hn, accv);
    if (lane == 0) OUT[n] = accv / (ssum + 1e-16f) + bias[0];
}

// -------------------- host launcher --------------------

extern "C" void kernel_launch(void* const* d_in, const int* in_sizes, int n_in,
                              void* d_out, int out_size, void* d_ws, size_t ws_size,
                              hipStream_t stream) {
    const float* x      = (const float*)d_in[0];
    const int*   ei     = (const int*)d_in[1];   // int32 per harness convention
    // d_in[2] = edge_attr: ignored by reference (no edge_dim)
    const float* W1  = (const float*)d_in[3];
    const float* as1 = (const float*)d_in[4];
    const float* ad1 = (const float*)d_in[5];
    const float* b1  = (const float*)d_in[6];
    const float* W2  = (const float*)d_in[7];
    const float* as2 = (const float*)d_in[8];
    const float* ad2 = (const float*)d_in[9];
    const float* b2  = (const float*)d_in[10];
    const float* W3  = (const float*)d_in[11];
    const float* as3 = (const float*)d_in[12];
    const float* ad3 = (const float*)d_in[13];
    const float* b3  = (const float*)d_in[14];

    const int N = in_sizes[0] / 256;   // 50000
    const int E = in_sizes[1] / 2;     // 1600000

    char* p = (char*)d_ws;
    auto alloc = [&](size_t bytes) -> void* {
        void* r = (void*)p;
        p += ((bytes + 255) / 256) * 256;
        return r;
    };
    int*   cntblk  = (int*)alloc(((size_t)NPAD + N) * 4);   // ncnt | ccur
    int*   ncnt    = cntblk;
    int*   ccur    = cntblk + NPAD;
    int*   rowptr  = (int*)alloc(((size_t)N + 1) * 4);
    int*   csr     = (int*)alloc((size_t)E * 4);
    unsigned short* hb = (unsigned short*)alloc((size_t)N * 64 * 2);  // bf16 H, 128B rows
    float* actbuf  = (float*)alloc((size_t)N * 48 * 4);               // act1
    float* h3      = (float*)alloc((size_t)N * 4);
    float* asrc    = (float*)alloc((size_t)N * 4);
    float* adst    = (float*)alloc((size_t)N * 4);

    // ---- CSR build + gemm1 ----
    hipMemsetAsync(cntblk, 0, ((size_t)NPAD + N) * 4, stream);
    int cblocks = (E + CTILE - 1) / CTILE;
    int gblocks = (N + 63) / 64;
    coarse_gemm1_kernel<256><<<cblocks + gblocks, 256, 0, stream>>>(
        ei, ncnt, E, cblocks, x, W1, as1, ad1, hb, asrc, adst, N);
    scan_kernel<<<1, 1024, 0, stream>>>(ncnt, rowptr, N);
    scatter_kernel<<<2048, 256, 0, stream>>>(ei, rowptr, ccur, csr, E);

    int ablocks = (N + 3) / 4;

    // ---- layer 1 agg: 48 cols, relu -> actbuf ----
    agg_pipe_kernel<48, true><<<ablocks, 256, 0, stream>>>(
        rowptr, csr, asrc, adst, hb, b1, actbuf, N);

    // ---- layer 2: 48 -> 60, relu, fused layer-3 GEMM in agg epilogue ----
    gemm_sgpr_kernel<48, 60, 15><<<gblocks, 256, 0, stream>>>(
        actbuf, W2, as2, ad2, hb, asrc, adst, N);
    agg_pipe_h3_kernel<<<ablocks, 256, 0, stream>>>(
        rowptr, csr, asrc, adst, hb, b2, W3, h3, N);

    // ---- layer 3 aggregation: straight to d_out ----
    agg1_kernel<<<ablocks, 256, 0, stream>>>(rowptr, csr, h3, as3, ad3, b3, (float*)d_out, N);
}

// Round 12
// 246.618 us; speedup vs baseline: 1.6926x; 1.6926x over previous
//
#include <hip/hip_runtime.h>
#include <cstdint>
#include <cstddef>

// ---------------------------------------------------------------------------
// GAT 3-layer forward, MI355X.
// Round 23: R22's classic CSR build regressed (scatter 127us: 4B stores to
// 50K open segments -> WRITE_SIZE 102MB, 16x write-allocate amplification).
// Locked-in lesson (R20+R22): the two-level bucketed sort is right BECAUSE
// staged writes are block-contiguous runs and fine_sort's csr writes are
// contiguous. Revert to R21 + one tweak inside the proven bin branch: phase 1
// packs each thread's <=32 edges (s,d both <2^16) into a static-indexed
// register array; phase 3 consumes registers -- deletes the second 12.8MB
// edge read and its 32-deep load->atomic->store latency chain. Rank-atomic
// ordering unchanged (same race as R21, replay-stable, verified twice).
// ---------------------------------------------------------------------------

__device__ __forceinline__ float leaky(float v) { return v > 0.f ? v : 0.2f * v; }

__device__ __forceinline__ unsigned short f2bf(float x) {
    unsigned int u = __float_as_uint(x);
    u = (u + 0x7FFFu + ((u >> 16) & 1u)) >> 16;   // RNE
    return (unsigned short)u;
}
__device__ __forceinline__ float bf2f(unsigned short b) {
    return __uint_as_float(((unsigned int)b) << 16);
}
__device__ __forceinline__ float bfhi(unsigned int d) {
    return __uint_as_float(d & 0xFFFF0000u);
}
__device__ __forceinline__ float bflo(unsigned int d) {
    return __uint_as_float(d << 16);
}

typedef _Float16 half8 __attribute__((ext_vector_type(8)));
typedef float f32x4 __attribute__((ext_vector_type(4)));

#define BSHIFT 7                 // 128 nodes per bucket
#define BCAP   5120              // slots per bucket region (mean 4096, +16 sigma)
#define CTILE  8192              // edges per coarse block (= 32 per thread)

// -------------------- fused: coarse bin (blocks < cblocks) + gemm1 MFMA ------

template <int FIN>
__global__ __launch_bounds__(256) void coarse_gemm1_kernel(
    const int* __restrict__ ei, unsigned int* __restrict__ staged,
    int* __restrict__ gcursor, int E, int K, int cblocks,
    const float* __restrict__ X, const float* __restrict__ W,
    const float* __restrict__ avs, const float* __restrict__ avd,
    unsigned short* __restrict__ hb, float* __restrict__ asrc,
    float* __restrict__ adst, int N) {

    if ((int)blockIdx.x < cblocks) {
        // ------ coarse bin (R21 3-phase, edges register-cached in phase 1) --
        __shared__ int hist[512];
        __shared__ int rank[512];
        __shared__ int base[512];
        for (int b = threadIdx.x; b < K; b += 256) { hist[b] = 0; rank[b] = 0; }
        __syncthreads();

        const int e0 = blockIdx.x * CTILE;
        const int e1 = min(E, e0 + CTILE);

        unsigned int ed[32];                 // packed s|d<<16; static indexing
#pragma unroll
        for (int i = 0; i < 32; i++) {
            int e = e0 + threadIdx.x + i * 256;
            unsigned int pk = 0xFFFFFFFFu;   // sentinel (d=0xFFFF >= N)
            if (e < e1) {
                int s = ei[e];
                int d = ei[E + e];
                pk = (unsigned int)s | ((unsigned int)d << 16);
                atomicAdd(&hist[d >> BSHIFT], 1);
            }
            ed[i] = pk;
        }
        __syncthreads();

        for (int b = threadIdx.x; b < K; b += 256) {
            int c = hist[b];
            base[b] = c ? atomicAdd(&gcursor[b], c) : 0;
        }
        __syncthreads();

#pragma unroll
        for (int i = 0; i < 32; i++) {
            unsigned int pk = ed[i];
            if (pk != 0xFFFFFFFFu) {
                int d = (int)(pk >> 16);
                int b = d >> BSHIFT;
                int r = atomicAdd(&rank[b], 1);
                staged[(size_t)b * BCAP + base[b] + r] =
                    ((unsigned int)(d & ((1 << BSHIFT) - 1)) << 16) | (pk & 0xFFFFu);
            }
        }
        return;
    }

    // ---------------- gemm1: MFMA, W-in-VGPR fp16 (R15, verbatim) ----------
    constexpr int FOUT = 48;
    constexpr int KK = FIN / 32;
    static_assert(FIN % 32 == 0, "FIN multiple of 32");

    const int bid  = (int)blockIdx.x - cblocks;
    const int wid  = __builtin_amdgcn_readfirstlane(threadIdx.x >> 6);
    const int lane = threadIdx.x & 63;
    const int col  = lane & 15;
    const int grp  = lane >> 4;
    const int wbase = bid * 64 + wid * 16;

    int arow = wbase + col;
    if (arow >= N) arow = N - 1;
    const float* xrow = X + (size_t)arow * FIN + grp * 8;

    half8 Bf[3][KK];
#pragma unroll
    for (int t = 0; t < 3; t++) {
#pragma unroll
        for (int kk = 0; kk < KK; kk++) {
            const float* wp = W + (size_t)(kk * 32 + grp * 8) * FOUT + t * 16 + col;
#pragma unroll
            for (int j = 0; j < 8; j++)
                Bf[t][kk][j] = (_Float16)wp[(size_t)j * FOUT];
        }
    }

    f32x4 acc0 = {0.f, 0.f, 0.f, 0.f};
    f32x4 acc1 = {0.f, 0.f, 0.f, 0.f};
    f32x4 acc2 = {0.f, 0.f, 0.f, 0.f};

#pragma unroll
    for (int kk = 0; kk < KK; kk++) {
        float4 xa = *(const float4*)(xrow + kk * 32);
        float4 xb = *(const float4*)(xrow + kk * 32 + 4);
        float xs[8] = {xa.x, xa.y, xa.z, xa.w, xb.x, xb.y, xb.z, xb.w};
        half8 ah, al;
#pragma unroll
        for (int j = 0; j < 8; j++) {
            _Float16 h = (_Float16)xs[j];
            ah[j] = h;
            al[j] = (_Float16)(xs[j] - (float)h);
        }
        acc0 = __builtin_amdgcn_mfma_f32_16x16x32_f16(ah, Bf[0][kk], acc0, 0, 0, 0);
        acc1 = __builtin_amdgcn_mfma_f32_16x16x32_f16(ah, Bf[1][kk], acc1, 0, 0, 0);
        acc2 = __builtin_amdgcn_mfma_f32_16x16x32_f16(ah, Bf[2][kk], acc2, 0, 0, 0);
        acc0 = __builtin_amdgcn_mfma_f32_16x16x32_f16(al, Bf[0][kk], acc0, 0, 0, 0);
        acc1 = __builtin_amdgcn_mfma_f32_16x16x32_f16(al, Bf[1][kk], acc1, 0, 0, 0);
        acc2 = __builtin_amdgcn_mfma_f32_16x16x32_f16(al, Bf[2][kk], acc2, 0, 0, 0);
    }

    float avs0 = avs[col], avs1 = avs[16 + col], avs2 = avs[32 + col];
    float avd0 = avd[col], avd1 = avd[16 + col], avd2 = avd[32 + col];

#pragma unroll
    for (int r = 0; r < 4; r++) {
        float ps = acc0[r] * avs0 + acc1[r] * avs1 + acc2[r] * avs2;
        float pd = acc0[r] * avd0 + acc1[r] * avd1 + acc2[r] * avd2;
#pragma unroll
        for (int off = 8; off; off >>= 1) {
            ps += __shfl_xor(ps, off, 64);
            pd += __shfl_xor(pd, off, 64);
        }
        int nd = wbase + grp * 4 + r;
        if (col == r && nd < N) { asrc[nd] = ps; adst[nd] = pd; }
    }

#pragma unroll
    for (int r = 0; r < 4; r++) {
        int nd = wbase + grp * 4 + r;
        if (nd < N) {
            unsigned short* hp = hb + (size_t)nd * 64 + col;
            hp[0]  = f2bf(acc0[r]);
            hp[16] = f2bf(acc1[r]);
            hp[32] = f2bf(acc2[r]);
        }
    }
}

// -------------------- fine pass (with integrated bucket-base reduction) -----

__global__ __launch_bounds__(256) void fine_sort_kernel(
    const unsigned int* __restrict__ staged, const int* __restrict__ gcursor,
    int* __restrict__ rowptr, int* __restrict__ csr, int N, int E) {
    __shared__ int cnt[128];
    __shared__ int off[128];
    __shared__ int gbred[4];
    __shared__ int lcsr[BCAP];
    const int b = blockIdx.x;
    const int t = threadIdx.x;
    const int c = gcursor[b];
    const unsigned int* rec = staged + (size_t)b * BCAP;

    // gb = sum_{i<b} gcursor[i]   (replaces the bucket_scan dispatch)
    int pacc = 0;
    for (int i = t; i < b; i += 256) pacc += gcursor[i];
#pragma unroll
    for (int o2 = 32; o2; o2 >>= 1) pacc += __shfl_xor(pacc, o2, 64);
    if ((t & 63) == 0) gbred[t >> 6] = pacc;

    if (t < 128) cnt[t] = 0;
    __syncthreads();
    const int gb = gbred[0] + gbred[1] + gbred[2] + gbred[3];

    for (int i = t; i < c; i += 256) atomicAdd(&cnt[rec[i] >> 16], 1);
    __syncthreads();

    if (t < 128) off[t] = cnt[t];
    __syncthreads();
    for (int s = 1; s < 128; s <<= 1) {
        int a = (t >= s && t < 128) ? off[t - s] : 0;
        __syncthreads();
        if (t < 128) off[t] += a;
        __syncthreads();
    }

    if (t < 128) {
        int excl = off[t] - cnt[t];
        int n = (b << BSHIFT) + t;
        if (n <= N) rowptr[n] = gb + excl;
        cnt[t] = excl;
    }
    if (b == 0 && t == 0) rowptr[N] = E;
    __syncthreads();

    for (int i = t; i < c; i += 256) {
        unsigned int r = rec[i];
        int p = atomicAdd(&cnt[r >> 16], 1);
        lcsr[p] = (int)(r & 0xFFFFu);
    }
    __syncthreads();

    for (int i = t; i < c; i += 256) csr[gb + i] = lcsr[i];
}

// -------------------- layer-2 GEMM (R12 structure: fout split, s_load W) ----

template <int FIN, int FOUT, int FT>
__global__ __launch_bounds__(256) void gemm_sgpr_kernel(
    const float* __restrict__ X, const float* __restrict__ W,
    const float* __restrict__ avs, const float* __restrict__ avd,
    unsigned short* __restrict__ hb, float* __restrict__ asrc, float* __restrict__ adst,
    int N) {
    static_assert(4 * FT == FOUT, "FT must be FOUT/4");
    __shared__ float red[2][4][64];

    const int wid  = __builtin_amdgcn_readfirstlane(threadIdx.x >> 6); // wave id 0..3
    const int lane = threadIdx.x & 63;
    const int n    = blockIdx.x * 64 + lane;
    const int nc   = (n < N) ? n : N - 1;     // clamp loads; stores guarded
    const int fbase = wid * FT;               // uniform

    const float* xrow = X + (size_t)nc * FIN;

    float acc[FT];
#pragma unroll
    for (int c = 0; c < FT; c++) acc[c] = 0.f;

#pragma unroll
    for (int k = 0; k < FIN; k += 4) {
        float4 xv = *(const float4*)(xrow + k);
        const float* w0 = W + (size_t)k * FOUT + fbase;   // uniform base
#pragma unroll
        for (int c = 0; c < FT; c++) {
            acc[c] = fmaf(xv.x, w0[c],            acc[c]);
            acc[c] = fmaf(xv.y, w0[FOUT + c],     acc[c]);
            acc[c] = fmaf(xv.z, w0[2 * FOUT + c], acc[c]);
            acc[c] = fmaf(xv.w, w0[3 * FOUT + c], acc[c]);
        }
    }

    // alpha partials over this wave's fout subset (avs/avd loads are uniform)
    float ps = 0.f, pd = 0.f;
#pragma unroll
    for (int c = 0; c < FT; c++) {
        ps = fmaf(acc[c], avs[fbase + c], ps);
        pd = fmaf(acc[c], avd[fbase + c], pd);
    }
    red[0][wid][lane] = ps;
    red[1][wid][lane] = pd;

    // h store (bf16, padded 64-entry rows)
    if (n < N) {
        if constexpr ((FT & 1) == 0) {
            unsigned int* dst = (unsigned int*)(hb + (size_t)n * 64 + fbase);
#pragma unroll
            for (int c = 0; c < FT; c += 2) {
                unsigned int pk = (unsigned int)f2bf(acc[c]) |
                                  ((unsigned int)f2bf(acc[c + 1]) << 16);
                dst[c >> 1] = pk;
            }
        } else {
#pragma unroll
            for (int c = 0; c < FT; c++)
                hb[(size_t)n * 64 + fbase + c] = f2bf(acc[c]);
        }
    }

    __syncthreads();
    if (threadIdx.x < 64 && n < N) {
        float s = red[0][0][lane] + red[0][1][lane] + red[0][2][lane] + red[0][3][lane];
        float d = red[1][0][lane] + red[1][1][lane] + red[1][2][lane] + red[1][3][lane];
        asrc[n] = s;
        adst[n] = d;
    }
}

// -------------------- pipelined gather step (R17) --------------------

#define GATHER_STEP(NG)                                                        \
    {                                                                          \
        int   off_[NG];                                                        \
        uint2 hd_[NG];                                                         \
        float ww_[NG];                                                         \
        _Pragma("unroll")                                                      \
        for (int u = 0; u < NG; u++) off_[u] = offlds[wv][4 * u + q];          \
        _Pragma("unroll")                                                      \
        for (int u = 0; u < NG; u++)                                           \
            hd_[u] = *(const uint2*)(hbb + ((unsigned int)off_[u] + suboff));  \
        float we = (lane < cnt) ? __expf(leaky(as + ad_n)) : 0.f;              \
        wpart += we;                                                           \
        wlds[wv][lane] = we;                                                   \
        _Pragma("unroll")                                                      \
        for (int u = 0; u < NG; u++) ww_[u] = wlds[wv][4 * u + q];             \
        _Pragma("unroll")                                                      \
        for (int u = 0; u < NG; u++) {                                         \
            a0 = fmaf(ww_[u], bflo(hd_[u].x), a0);                             \
            a1 = fmaf(ww_[u], bfhi(hd_[u].x), a1);                             \
            a2 = fmaf(ww_[u], bflo(hd_[u].y), a2);                             \
            a3 = fmaf(ww_[u], bfhi(hd_[u].y), a3);                             \
        }                                                                      \
    }

// -------------------- pipelined quad-edge aggregation (R17) --------------------

template <int FOUT, bool RELU>
__global__ __launch_bounds__(256) void agg_pipe_kernel(
    const int* __restrict__ rowptr, const int* __restrict__ csr,
    const float* __restrict__ asrc, const float* __restrict__ adst,
    const unsigned short* __restrict__ hb, const float* __restrict__ bias,
    float* __restrict__ OUT, int N) {
    constexpr int NSUB = FOUT / 4;
    static_assert(FOUT % 4 == 0, "FOUT multiple of 4");
    __shared__ int   offlds[4][64];
    __shared__ float wlds[4][64];
    const int wv = threadIdx.x >> 6;
    int n = blockIdx.x * 4 + wv;
    if (n >= N) return;
    const int lane = threadIdx.x & 63;
    const int q    = lane >> 4;            // quarter 0..3 -> slot 4u+q
    const int sub  = lane & 15;
    const int subc = (sub < NSUB) ? sub : NSUB - 1;   // clamp: no padding fetch
    const unsigned int suboff = (unsigned int)subc * 8;
    const int rs = rowptr[n], re = rowptr[n + 1];
    const float ad_n = adst[n];
    const float wself = __expf(leaky(asrc[n] + ad_n));
    const char* hbb = (const char*)hb;

    float a0 = 0.f, a1 = 0.f, a2 = 0.f, a3 = 0.f;
    float wpart = 0.f;

    for (int base = rs; base < re; base += 64) {
        const int cnt = min(64, re - base);
        int ce = base + lane;
        if (ce >= re) ce = re - 1;                  // clamp load addr
        int sv = csr[ce];
        int sidx = (lane < cnt) ? sv : n;           // padded -> self row (w=0)
        offlds[wv][lane] = sidx << 7;
        float as = asrc[sidx];
        if (cnt <= 32) { GATHER_STEP(8) } else { GATHER_STEP(16) }
    }

    // softmax denominator
#pragma unroll
    for (int off = 32; off; off >>= 1) wpart += __shfl_xor(wpart, off, 64);
    const float ssum = wpart + wself;

    // combine quarters -> all lanes hold full sums for their sub
    a0 += __shfl_xor(a0, 16, 64); a0 += __shfl_xor(a0, 32, 64);
    a1 += __shfl_xor(a1, 16, 64); a1 += __shfl_xor(a1, 32, 64);
    a2 += __shfl_xor(a2, 16, 64); a2 += __shfl_xor(a2, 32, 64);
    a3 += __shfl_xor(a3, 16, 64); a3 += __shfl_xor(a3, 32, 64);

    // self term (post-combine: counted once)
    {
        uint2 sv = *(const uint2*)(hbb + (((unsigned int)n << 7) + suboff));
        a0 = fmaf(wself, bflo(sv.x), a0);
        a1 = fmaf(wself, bfhi(sv.x), a1);
        a2 = fmaf(wself, bflo(sv.y), a2);
        a3 = fmaf(wself, bfhi(sv.y), a3);
    }

    if (lane < NSUB) {                     // quarter 0, valid subs only
        const float inv = 1.f / (ssum + 1e-16f);
        float4 bv = *(const float4*)(bias + sub * 4);
        float4 o;
        o.x = a0 * inv + bv.x;
        o.y = a1 * inv + bv.y;
        o.z = a2 * inv + bv.z;
        o.w = a3 * inv + bv.w;
        if (RELU) {
            o.x = fmaxf(o.x, 0.f); o.y = fmaxf(o.y, 0.f);
            o.z = fmaxf(o.z, 0.f); o.w = fmaxf(o.w, 0.f);
        }
        *(float4*)(OUT + (size_t)n * FOUT + sub * 4) = o;
    }
}

// -------------------- pipelined agg layer 2, fused layer-3 GEMM (R17) -------

__global__ __launch_bounds__(256) void agg_pipe_h3_kernel(
    const int* __restrict__ rowptr, const int* __restrict__ csr,
    const float* __restrict__ asrc, const float* __restrict__ adst,
    const unsigned short* __restrict__ hb, const float* __restrict__ bias,
    const float* __restrict__ W3, float* __restrict__ h3, int N) {
    constexpr int FOUT = 60;
    constexpr int NSUB = FOUT / 4;         // 15
    __shared__ int   offlds[4][64];
    __shared__ float wlds[4][64];
    const int wv = threadIdx.x >> 6;
    int n = blockIdx.x * 4 + wv;
    if (n >= N) return;
    const int lane = threadIdx.x & 63;
    const int q    = lane >> 4;
    const int sub  = lane & 15;
    const int subc = (sub < NSUB) ? sub : NSUB - 1;
    const unsigned int suboff = (unsigned int)subc * 8;
    const int rs = rowptr[n], re = rowptr[n + 1];
    const float ad_n = adst[n];
    const float wself = __expf(leaky(asrc[n] + ad_n));
    const char* hbb = (const char*)hb;

    float a0 = 0.f, a1 = 0.f, a2 = 0.f, a3 = 0.f;
    float wpart = 0.f;

    for (int base = rs; base < re; base += 64) {
        const int cnt = min(64, re - base);
        int ce = base + lane;
        if (ce >= re) ce = re - 1;
        int sv = csr[ce];
        int sidx = (lane < cnt) ? sv : n;
        offlds[wv][lane] = sidx << 7;
        float as = asrc[sidx];
        if (cnt <= 32) { GATHER_STEP(8) } else { GATHER_STEP(16) }
    }

#pragma unroll
    for (int off = 32; off; off >>= 1) wpart += __shfl_xor(wpart, off, 64);
    const float ssum = wpart + wself;

    a0 += __shfl_xor(a0, 16, 64); a0 += __shfl_xor(a0, 32, 64);
    a1 += __shfl_xor(a1, 16, 64); a1 += __shfl_xor(a1, 32, 64);
    a2 += __shfl_xor(a2, 16, 64); a2 += __shfl_xor(a2, 32, 64);
    a3 += __shfl_xor(a3, 16, 64); a3 += __shfl_xor(a3, 32, 64);

    {
        uint2 sv = *(const uint2*)(hbb + (((unsigned int)n << 7) + suboff));
        a0 = fmaf(wself, bflo(sv.x), a0);
        a1 = fmaf(wself, bfhi(sv.x), a1);
        a2 = fmaf(wself, bflo(sv.y), a2);
        a3 = fmaf(wself, bfhi(sv.y), a3);
    }

    // act2 = relu(acc/ssum + bias); fold layer-3 GEMM: t = dot(act2, W3)
    float t = 0.f;
    {
        const float inv = 1.f / (ssum + 1e-16f);
        float4 bv = *(const float4*)(bias + subc * 4);
        float4 wv3 = *(const float4*)(W3 + subc * 4);
        float o0 = fmaxf(a0 * inv + bv.x, 0.f);
        float o1 = fmaxf(a1 * inv + bv.y, 0.f);
        float o2 = fmaxf(a2 * inv + bv.z, 0.f);
        float o3 = fmaxf(a3 * inv + bv.w, 0.f);
        if (sub < NSUB)
            t = o0 * wv3.x + o1 * wv3.y + o2 * wv3.z + o3 * wv3.w;
    }
#pragma unroll
    for (int off = 8; off; off >>= 1) t += __shfl_xor(t, off, 64);   // within quarter
    if (lane == 0) h3[n] = t;
}

// -------------------- layer-3 aggregation --------------------

__global__ __launch_bounds__(256) void agg1_kernel(
    const int* __restrict__ rowptr, const int* __restrict__ csr,
    const float* __restrict__ h3,
    const float* __restrict__ as3p, const float* __restrict__ ad3p,
    const float* __restrict__ bias, float* __restrict__ OUT, int N) {
    int n = blockIdx.x * 4 + (threadIdx.x >> 6);
    if (n >= N) return;
    int lane = threadIdx.x & 63;
    int rs = rowptr[n], re = rowptr[n + 1];
    const float a_s = as3p[0];
    float hn = h3[n];
    float adn = ad3p[0] * hn;
    float wself = __expf(leaky(a_s * hn + adn));

    float ssum = 0.f, accv = 0.f;
    for (int e = rs + lane; e < re; e += 64) {
        float hs = h3[csr[e]];
        float w = __expf(leaky(a_s * hs + adn));
        ssum += w;
        accv = fmaf(w, hs, accv);
    }
#pragma unroll
    for (int off = 32; off; off >>= 1) {
        ssum += __shfl_xor(ssum, off, 64);
        accv += __shfl_xor(accv, off, 64);
    }
    ssum += wself;
    accv = fmaf(wself, hn, accv);
    if (lane == 0) OUT[n] = accv / (ssum + 1e-16f) + bias[0];
}

// -------------------- host launcher --------------------

extern "C" void kernel_launch(void* const* d_in, const int* in_sizes, int n_in,
                              void* d_out, int out_size, void* d_ws, size_t ws_size,
                              hipStream_t stream) {
    const float* x      = (const float*)d_in[0];
    const int*   ei     = (const int*)d_in[1];   // int32 per harness convention
    // d_in[2] = edge_attr: ignored by reference (no edge_dim)
    const float* W1  = (const float*)d_in[3];
    const float* as1 = (const float*)d_in[4];
    const float* ad1 = (const float*)d_in[5];
    const float* b1  = (const float*)d_in[6];
    const float* W2  = (const float*)d_in[7];
    const float* as2 = (const float*)d_in[8];
    const float* ad2 = (const float*)d_in[9];
    const float* b2  = (const float*)d_in[10];
    const float* W3  = (const float*)d_in[11];
    const float* as3 = (const float*)d_in[12];
    const float* ad3 = (const float*)d_in[13];
    const float* b3  = (const float*)d_in[14];

    const int N = in_sizes[0] / 256;   // 50000
    const int E = in_sizes[1] / 2;     // 1600000
    const int K = (N + (1 << BSHIFT) - 1) >> BSHIFT;   // 391 buckets

    char* p = (char*)d_ws;
    auto alloc = [&](size_t bytes) -> void* {
        void* r = (void*)p;
        p += ((bytes + 255) / 256) * 256;
        return r;
    };
    int*   gcursor = (int*)alloc(512 * 4);
    int*   rowptr  = (int*)alloc(((size_t)N + 1) * 4);
    int*   csr     = (int*)alloc((size_t)E * 4);
    unsigned short* hb = (unsigned short*)alloc((size_t)N * 64 * 2);  // bf16 H, 128B rows
    float* actbuf  = (float*)alloc((size_t)N * 48 * 4);               // act1 only
    float* h3      = (float*)alloc((size_t)N * 4);
    float* asrc    = (float*)alloc((size_t)N * 4);
    float* adst    = (float*)alloc((size_t)N * 4);
    // staged bucket regions (8 MB) alias actbuf (9.6 MB, dead until first agg):
    unsigned int* staged = (unsigned int*)actbuf;

    // ---- CSR build + gemm1 (fused dispatch: disjoint outputs, overlap) ----
    hipMemsetAsync(gcursor, 0, 512 * 4, stream);
    int cblocks = (E + CTILE - 1) / CTILE;
    int gblocks = (N + 63) / 64;
    coarse_gemm1_kernel<256><<<cblocks + gblocks, 256, 0, stream>>>(
        ei, staged, gcursor, E, K, cblocks,
        x, W1, as1, ad1, hb, asrc, adst, N);
    fine_sort_kernel<<<K, 256, 0, stream>>>(staged, gcursor, rowptr, csr, N, E);

    int ablocks = (N + 3) / 4;

    // ---- layer 1 agg: 48 cols, relu -> actbuf ----
    agg_pipe_kernel<48, true><<<ablocks, 256, 0, stream>>>(
        rowptr, csr, asrc, adst, hb, b1, actbuf, N);

    // ---- layer 2: 48 -> 60, relu, fused layer-3 GEMM in agg epilogue ----
    gemm_sgpr_kernel<48, 60, 15><<<gblocks, 256, 0, stream>>>(
        actbuf, W2, as2, ad2, hb, asrc, adst, N);
    agg_pipe_h3_kernel<<<ablocks, 256, 0, stream>>>(
        rowptr, csr, asrc, adst, hb, b2, W3, h3, N);

    // ---- layer 3 aggregation: straight to d_out ----
    agg1_kernel<<<ablocks, 256, 0, stream>>>(rowptr, csr, h3, as3, ad3, b3, (float*)d_out, N);
}